// Round 1
// 300.167 us; speedup vs baseline: 1.1146x; 1.1146x over previous
//
#include <hip/hip_runtime.h>

typedef __attribute__((ext_vector_type(8))) short short8;
typedef __attribute__((ext_vector_type(4))) float floatx4;

namespace {
constexpr int kB = 32, kCin = 256, kCout = 512, kL = 2048;
constexpr float kEps = 1e-5f;
constexpr float kInvN = 1.0f / (float)(kB * kL);   // 1/65536
constexpr int kKtot = kB * kL;                     // 65536
constexpr int BK = 32;
constexpr int KSTEPS = kCin / BK;                  // 8
constexpr int ST = 44;                             // padded LDS row stride (ushorts) for B tiles
constexpr int GRID_OUT = 4 * (kL / 128) * kB;      // 2048

// ---- main ws layout (float units). Total 48.8 MiB (fits a 64 MiB ws; old W2 was 64.25 MiB). ----
constexpr size_t W_ZC    = 0;           // ushort Zc[256][65536]   -> 8,388,608 floats
constexpr size_t W_GPART = 8388608;     // float Gpart[256][16384] -> 4,194,304 floats
constexpr size_t W_G     = 12582912;    // float G[256*256]
constexpr size_t W_SZ    = 12648448;    // float Sz[256]
constexpr size_t W_SC    = 12648704;    // float sc[512]
constexpr size_t W_SH    = 12649216;    // float sh[512]
constexpr size_t W_WBF   = 12649728;    // ushort Wbf[2][512][256] -> 131,072 floats
constexpr size_t W_END   = 12780800;
constexpr size_t W_BYTES = W_END * 4ull;           // 51,123,200 B

// ---- fallback ws layout (floats) ----
constexpr size_t F_G = 0, F_SZ = 65536, F_SC = 65792, F_SH = 66304, F_WBF = 66816;
constexpr size_t F_END = 197888;                   // F_WBF + 131072
constexpr size_t F_BYTES = F_END * 4ull;           // ~791 KB
}

__device__ inline unsigned short f2bf(float f) {
    union { float f; unsigned u; } v; v.f = f;
    return (unsigned short)((v.u + 0x7fffu + ((v.u >> 16) & 1u)) >> 16);  // RNE
}
__device__ inline float bf2f(unsigned short h) {
    union { unsigned u; float f; } v; v.u = ((unsigned)h) << 16; return v.f;
}
__device__ inline unsigned pack2(float lo, float hi) {
    return (unsigned)f2bf(lo) | ((unsigned)f2bf(hi) << 16);
}
// single-instruction packed f32->bf16 (RNE), lo -> bits[15:0], hi -> bits[31:16]
__device__ inline unsigned cvtpk(float lo, float hi) {
    unsigned r;
    asm("v_cvt_pk_bf16_f32 %0, %1, %2" : "=v"(r) : "v"(lo), "v"(hi));
    return r;
}
// async 16B global->LDS (lane i lands at wave-uniform lds_base + i*16)
__device__ inline void cp16(const void* g, void* l) {
    __builtin_amdgcn_global_load_lds(
        (const __attribute__((address_space(1))) unsigned int*)g,
        (__attribute__((address_space(3))) unsigned int*)l, 16, 0, 0);
}

// ============================================================ init: weights -> bf16, zero Sz + G
__global__ __launch_bounds__(256) void k_init(
    const float* __restrict__ pw_w, const float* __restrict__ res_w,
    unsigned short* __restrict__ Wbf, float* __restrict__ Sz, float* __restrict__ G)
{
    const int bid = blockIdx.x, tid = threadIdx.x;
    if (bid < 128) {
        const float* src = (bid < 64) ? pw_w : res_w;
        const int i = (bid & 63) * 2048 + tid * 8;
        float4 a = *(const float4*)(src + i);
        float4 b = *(const float4*)(src + i + 4);
        union { unsigned short u[8]; short8 v; } o;
        o.u[0]=f2bf(a.x); o.u[1]=f2bf(a.y); o.u[2]=f2bf(a.z); o.u[3]=f2bf(a.w);
        o.u[4]=f2bf(b.x); o.u[5]=f2bf(b.y); o.u[6]=f2bf(b.z); o.u[7]=f2bf(b.w);
        *(short8*)(Wbf + (bid < 64 ? 0 : 131072) + i) = o.v;
    } else if (bid == 128) {
        Sz[tid] = 0.f;
    } else {
        const int i = (bid - 129) * 2048 + tid * 8;
        float4 z4 = make_float4(0.f, 0.f, 0.f, 0.f);
        *(float4*)(G + i) = z4;
        *(float4*)(G + i + 4) = z4;
    }
}

// ============================================================ prep: x -> Zc bf16 [c][b*L], + Sz sums
__global__ __launch_bounds__(256, 4) void k_prepc(
    const float* __restrict__ x, const float* __restrict__ sw,
    unsigned short* __restrict__ Zc, float* __restrict__ Sz)
{
    __shared__ float wred[4];
    const int tid = threadIdx.x;
    const int lane = tid & 63, wave = tid >> 6;
    const int c = blockIdx.x >> 5;   // 0..255
    const int b = blockIdx.x & 31;   // 0..31
    const float w0 = sw[0], w1 = sw[1], w2 = sw[2];
    const int l = tid * 8;
    const float* xr = x + ((size_t)b * kCin + c) * kL + l;
    float4 c0 = *(const float4*)xr;
    float4 c1 = *(const float4*)(xr + 4);
    float4 pv = (l >= 4) ? *(const float4*)(xr - 4) : make_float4(0.f, 0.f, 0.f, 0.f);
    float V[12] = {pv.x,pv.y,pv.z,pv.w, c0.x,c0.y,c0.z,c0.w, c1.x,c1.y,c1.z,c1.w};
    union { unsigned short u[8]; short8 v; } o;
    float s = 0.f;
    #pragma unroll
    for (int j = 0; j < 8; ++j) {
        float z = fmaf(w0, V[j], fmaf(w1, V[j + 2], w2 * V[j + 4]));
        o.u[j] = f2bf(z);
        s += z;
    }
    *(short8*)(Zc + ((size_t)c << 16) + b * kL + l) = o.v;
    #pragma unroll
    for (int m = 1; m <= 32; m <<= 1) s += __shfl_xor(s, m, 64);
    if (lane == 0) wred[wave] = s;
    __syncthreads();
    if (tid == 0) atomicAdd(&Sz[c], (wred[0] + wred[1]) + (wred[2] + wred[3]));
}

// ============================================================ Gram GEMM: double-buffered cp16 staging,
// granule-swizzled LDS (2-way max bank conflict). 64 chunks x 1024k x 4 quads = 256 blocks.
__global__ __launch_bounds__(256, 2) void k_gram2(
    const unsigned short* __restrict__ Zc, float* __restrict__ Gpart)
{
    __shared__ __align__(16) unsigned short Zm[2][128 * 32];
    __shared__ __align__(16) unsigned short Zn[2][128 * 32];

    const int tid = threadIdx.x;
    const int lane = tid & 63, wave = tid >> 6;
    const int fr = lane & 15, fq = lane >> 4;
    const int q = blockIdx.x & 3;
    const int h = blockIdx.x >> 2;         // 0..63, 1024 k each
    const int qm = (q >> 1) * 128, qn = (q & 1) * 128;
    const int wm = (wave >> 1) * 64, wn = (wave & 1) * 64;

    const int srow = wave * 32 + (lane >> 2);
    // source granule XOR matches read-side swizzle: s(row) = (row>>1)&3 = (lane>>3)&3 here
    const int gsw = (((lane & 3) ^ ((lane >> 3) & 3)) * 8);
    const size_t kbase = (size_t)h * 1024 + gsw;
    const unsigned short* gm0 = Zc + (size_t)(qm + srow) * kKtot + kbase;
    const unsigned short* gm1 = gm0 + (size_t)16 * kKtot;
    const unsigned short* gn0 = Zc + (size_t)(qn + srow) * kKtot + kbase;
    const unsigned short* gn1 = gn0 + (size_t)16 * kKtot;

    unsigned short* zm0 = &Zm[0][wave * 1024];
    unsigned short* zm1 = &Zm[1][wave * 1024];
    unsigned short* zn0 = &Zn[0][wave * 1024];
    unsigned short* zn1 = &Zn[1][wave * 1024];

    const int rsw = (fr >> 1) & 3;
    int aoff[4], boff[4];
    #pragma unroll
    for (int mi = 0; mi < 4; ++mi) aoff[mi] = (wm + mi * 16 + fr) * 32 + ((fq ^ rsw) * 8);
    #pragma unroll
    for (int ni = 0; ni < 4; ++ni) boff[ni] = (wn + ni * 16 + fr) * 32 + ((fq ^ rsw) * 8);

    floatx4 acc[4][4];
    #pragma unroll
    for (int mi = 0; mi < 4; ++mi)
        #pragma unroll
        for (int ni = 0; ni < 4; ++ni) acc[mi][ni] = (floatx4){0.f, 0.f, 0.f, 0.f};

    auto STAGE = [&](unsigned short* m0, unsigned short* n0) {
        cp16(gm0, m0); cp16(gm1, m0 + 512);
        cp16(gn0, n0); cp16(gn1, n0 + 512);
        gm0 += 32; gm1 += 32; gn0 += 32; gn1 += 32;
    };

    STAGE(zm0, zn0);
    for (int t = 0; t < 32; ++t) {
        __syncthreads();                         // drains cp16 of tile t; protects buffer reuse
        if (t < 31) { if (t & 1) STAGE(zm0, zn0); else STAGE(zm1, zn1); }
        const unsigned short* rm = (t & 1) ? &Zm[1][0] : &Zm[0][0];
        const unsigned short* rn = (t & 1) ? &Zn[1][0] : &Zn[0][0];
        short8 bfp[4];
        #pragma unroll
        for (int ni = 0; ni < 4; ++ni)
            bfp[ni] = *(const short8*)&rn[boff[ni]];
        #pragma unroll
        for (int mi = 0; mi < 4; ++mi) {
            short8 af = *(const short8*)&rm[aoff[mi]];
            #pragma unroll
            for (int ni = 0; ni < 4; ++ni)
                acc[mi][ni] = __builtin_amdgcn_mfma_f32_16x16x32_bf16(af, bfp[ni], acc[mi][ni], 0, 0, 0);
        }
    }

    float* gp = Gpart + (size_t)blockIdx.x * 16384;
    #pragma unroll
    for (int mi = 0; mi < 4; ++mi)
        #pragma unroll
        for (int ni = 0; ni < 4; ++ni) {
            const int col = wn + ni * 16 + fr;
            #pragma unroll
            for (int r = 0; r < 4; ++r)
                gp[(wm + mi * 16 + fq * 4 + r) * 128 + col] = acc[mi][ni][r];
        }
}

// ============================================================ reduce Gpart -> G (64 h-chunks)
__global__ __launch_bounds__(256) void k_gred(const float* __restrict__ Gpart, float* __restrict__ G)
{
    const int q = blockIdx.x >> 6;
    const int e = (blockIdx.x & 63) * 256 + threadIdx.x;   // 0..16383
    const int qm = (q >> 1) * 128, qn = (q & 1) * 128;
    const float* p = Gpart + (size_t)q * 16384 + e;
    float s0 = 0.f, s1 = 0.f, s2 = 0.f, s3 = 0.f;
    #pragma unroll 4
    for (int hh = 0; hh < 64; hh += 4) {
        s0 += p[(size_t)(hh + 0) * 65536];
        s1 += p[(size_t)(hh + 1) * 65536];
        s2 += p[(size_t)(hh + 2) * 65536];
        s3 += p[(size_t)(hh + 3) * 65536];
    }
    G[(qm + (e >> 7)) * 256 + qn + (e & 127)] = (s0 + s1) + (s2 + s3);
}

// ============================================================ BN params: mean = w.Sz/N, E[y2] = wGw/N
__global__ __launch_bounds__(256) void k_bnp(
    const float* __restrict__ G, const float* __restrict__ Sz,
    const unsigned short* __restrict__ Wbf, const float* __restrict__ gamma,
    const float* __restrict__ beta, float* __restrict__ sc_out, float* __restrict__ sh_out)
{
    __shared__ float t[256];
    __shared__ float redq[4], redm[4];
    const int o = blockIdx.x, c = threadIdx.x;
    const int lane = c & 63, wave = c >> 6;
    t[c] = bf2f(Wbf[(size_t)o * kCin + c]);
    __syncthreads();
    const float myt = t[c];
    float q0 = 0.f, q1 = 0.f, q2 = 0.f, q3 = 0.f;       // 4 chains: break serial FMA dependency
    #pragma unroll 4
    for (int j = 0; j < 256; j += 4) {
        q0 = fmaf(t[j + 0], G[(j + 0) * 256 + c], q0);
        q1 = fmaf(t[j + 1], G[(j + 1) * 256 + c], q1);
        q2 = fmaf(t[j + 2], G[(j + 2) * 256 + c], q2);
        q3 = fmaf(t[j + 3], G[(j + 3) * 256 + c], q3);
    }
    float q = ((q0 + q1) + (q2 + q3)) * myt;
    float m = myt * Sz[c];
    #pragma unroll
    for (int off = 1; off <= 32; off <<= 1) {
        q += __shfl_xor(q, off, 64);
        m += __shfl_xor(m, off, 64);
    }
    if (lane == 0) { redq[wave] = q; redm[wave] = m; }
    __syncthreads();
    if (c == 0) {
        const float qt = (redq[0] + redq[1]) + (redq[2] + redq[3]);
        const float mt = (redm[0] + redm[1]) + (redm[2] + redm[3]);
        const float mean = mt * kInvN;
        const float var = qt * kInvN - mean * mean;
        const float s = gamma[o] * rsqrtf(var + kEps);
        sc_out[o] = s;
        sh_out[o] = fmaf(-mean, s, beta[o]);
    }
}

// ============================================================ fallback gram (R3 VALU version)
__global__ __launch_bounds__(256, 2) void k_gram_fb(
    const float* __restrict__ x, const float* __restrict__ sw,
    float* __restrict__ G, float* __restrict__ Sz)
{
    __shared__ __align__(16) unsigned short Zt[256 * ST];
    const int tid = threadIdx.x;
    const int lane = tid & 63, wave = tid >> 6;
    const int fr = lane & 15, fq = lane >> 4;
    const int quad = blockIdx.x & 3;
    const int chunk = blockIdx.x >> 2;
    const int qm = (quad >> 1) * 128, qn = (quad & 1) * 128;
    const int b = chunk >> 2;
    const int l0 = (chunk & 3) * 512;
    const bool dosz = (quad == 0);
    const float w0 = sw[0], w1 = sw[1], w2 = sw[2];
    const float* xb = x + (size_t)b * kCin * kL;

    floatx4 acc[4][4];
    #pragma unroll
    for (int mi = 0; mi < 4; ++mi)
        #pragma unroll
        for (int ni = 0; ni < 4; ++ni) acc[mi][ni] = (floatx4){0.f, 0.f, 0.f, 0.f};

    const int cr = tid >> 3;
    const int loff = (tid & 7) * 4;
    float sz[8] = {0.f,0.f,0.f,0.f,0.f,0.f,0.f,0.f};
    int aOff[4], bOff[4];
    #pragma unroll
    for (int mi = 0; mi < 4; ++mi) aOff[mi] = (qm + (wave >> 1) * 64 + mi * 16 + fr) * ST + fq * 8;
    #pragma unroll
    for (int ni = 0; ni < 4; ++ni) bOff[ni] = (qn + (wave & 1) * 64 + ni * 16 + fr) * ST + fq * 8;

    for (int ks = 0; ks < 16; ++ks) {
        const int lk = l0 + ks * BK;
        const bool hasprv = (lk + loff) >= 4;
        __syncthreads();
        #pragma unroll
        for (int p = 0; p < 8; ++p) {
            const int c = p * 32 + cr;
            const float* bp = xb + (size_t)c * kL + lk + loff;
            float4 cur = *(const float4*)bp;
            float4 prv = hasprv ? *(const float4*)(bp - 4) : make_float4(0.f,0.f,0.f,0.f);
            float z0 = fmaf(w0, prv.x, fmaf(w1, prv.z, w2 * cur.x));
            float z1 = fmaf(w0, prv.y, fmaf(w1, prv.w, w2 * cur.y));
            float z2 = fmaf(w0, prv.z, fmaf(w1, cur.x, w2 * cur.z));
            float z3 = fmaf(w0, prv.w, fmaf(w1, cur.y, w2 * cur.w));
            *(unsigned*)&Zt[c * ST + loff]     = pack2(z0, z1);
            *(unsigned*)&Zt[c * ST + loff + 2] = pack2(z2, z3);
            if (dosz) sz[p] += (z0 + z1) + (z2 + z3);
        }
        __syncthreads();
        short8 bf_[4];
        #pragma unroll
        for (int ni = 0; ni < 4; ++ni) bf_[ni] = *(const short8*)&Zt[bOff[ni]];
        #pragma unroll
        for (int mi = 0; mi < 4; ++mi) {
            short8 af = *(const short8*)&Zt[aOff[mi]];
            #pragma unroll
            for (int ni = 0; ni < 4; ++ni)
                acc[mi][ni] = __builtin_amdgcn_mfma_f32_16x16x32_bf16(af, bf_[ni], acc[mi][ni], 0, 0, 0);
        }
    }
    #pragma unroll
    for (int mi = 0; mi < 4; ++mi) {
        const int growb = qm + (wave >> 1) * 64 + mi * 16 + fq * 4;
        #pragma unroll
        for (int ni = 0; ni < 4; ++ni) {
            const int gcol = qn + (wave & 1) * 64 + ni * 16 + fr;
            #pragma unroll
            for (int r = 0; r < 4; ++r)
                atomicAdd(&G[(growb + r) * 256 + gcol], acc[mi][ni][r]);
        }
    }
    if (dosz) {
        #pragma unroll
        for (int p = 0; p < 8; ++p) {
            float s = sz[p];
            s += __shfl_xor(s, 1, 64);
            s += __shfl_xor(s, 2, 64);
            s += __shfl_xor(s, 4, 64);
            if ((lane & 7) == 0) atomicAdd(&Sz[p * 32 + cr], s);
        }
    }
}

// ============================================================ output: 128x128 dual GEMM
// A (both weight matrices) staged via cp16 from precomputed bf16 (granule-XOR swizzle);
// B packed from x via v_cvt_pk_bf16_f32; XCD-grouping block swizzle.
__global__ __launch_bounds__(256, 2) void k_out2(
    const float* __restrict__ x, const float* __restrict__ sw,
    const unsigned short* __restrict__ Wbf,
    const float* __restrict__ res_b, const float* __restrict__ sc_arr,
    const float* __restrict__ sh_arr, float* __restrict__ out)
{
    __shared__ __align__(16) unsigned short As[2 * 128 * 32];  // [P|R][row][32c], swizzled granules
    __shared__ __align__(16) unsigned short Bz[128 * ST];
    __shared__ __align__(16) unsigned short Bx[128 * ST];

    const int tid = threadIdx.x;
    const int lane = tid & 63, wave = tid >> 6;
    const int fr = lane & 15, fq = lane >> 4;
    const int wo = (wave >> 1) * 64;
    const int wl = (wave & 1) * 64;

    // XCD-grouped decode: 4 o-tile blocks sharing an x-slice land adjacent on the same XCD
    const int pid = blockIdx.x;
    const int slot = pid >> 3;
    const int mt = slot & 3;
    const int u = (pid & 7) * 64 + (slot >> 2);    // 0..511 unit = (b,lt)
    const int lt = u & 15;
    const int b = u >> 4;
    const int o0 = mt * 128, l0 = lt * 128;

    const float w0 = sw[0], w1 = sw[1], w2 = sw[2];
    const float* xb = x + (size_t)b * kCin * kL;

    floatx4 accY[4][4], accR[4][4];
    #pragma unroll
    for (int mi = 0; mi < 4; ++mi)
        #pragma unroll
        for (int ni = 0; ni < 4; ++ni) {
            accY[mi][ni] = (floatx4){0.f, 0.f, 0.f, 0.f};
            accR[mi][ni] = (floatx4){0.f, 0.f, 0.f, 0.f};
        }

    // ---- A staging: 4 cp16/thread/kstep, linear LDS dest + XOR'd global source granule ----
    const int gsw = (((lane & 3) ^ ((lane >> 3) & 3)) * 8);
    const unsigned short* wsrc[4];
    unsigned short* wdst[4];
    #pragma unroll
    for (int j = 0; j < 4; ++j) {
        const int m = j >> 1;
        const int r = (j & 1) * 64 + wave * 16 + (lane >> 2);
        wsrc[j] = Wbf + (size_t)m * 131072 + (size_t)(o0 + r) * kCin + gsw;
        wdst[j] = As + j * 2048 + wave * 512;      // wave-uniform base; HW adds lane*16B
    }

    // ---- fragment read offsets ----
    const int rsw = (fr >> 1) & 3;
    int aOffP[4], bOff[4];
    #pragma unroll
    for (int mi = 0; mi < 4; ++mi)
        aOffP[mi] = (wo + mi * 16 + fr) * 32 + ((fq ^ rsw) * 8);
    #pragma unroll
    for (int ni = 0; ni < 4; ++ni) bOff[ni] = (wl + ni * 16 + fr) * ST + fq * 8;

    // ---- B prefetch regs ----
    const int c2 = (tid & 15) * 2;
    const int ll = (tid >> 4) * 8;
    const bool hasprv = (l0 + ll) >= 4;
    float4 xpa, xa0, xa1, xpb, xb0, xb1;
    auto LOAD = [&](int ks) {
        const int k0 = ks * BK;
        const float* base0 = xb + (size_t)(k0 + c2) * kL + l0 + ll;
        const float* base1 = base0 + kL;
        xpa = hasprv ? *(const float4*)(base0 - 4) : make_float4(0.f,0.f,0.f,0.f);
        xa0 = *(const float4*)(base0);
        xa1 = *(const float4*)(base0 + 4);
        xpb = hasprv ? *(const float4*)(base1 - 4) : make_float4(0.f,0.f,0.f,0.f);
        xb0 = *(const float4*)(base1);
        xb1 = *(const float4*)(base1 + 4);
    };
    auto PACKB = [&]() {
        float A[12]  = {xpa.x,xpa.y,xpa.z,xpa.w, xa0.x,xa0.y,xa0.z,xa0.w, xa1.x,xa1.y,xa1.z,xa1.w};
        float Bv[12] = {xpb.x,xpb.y,xpb.z,xpb.w, xb0.x,xb0.y,xb0.z,xb0.w, xb1.x,xb1.y,xb1.z,xb1.w};
        #pragma unroll
        for (int j = 0; j < 8; ++j) {
            float zA = fmaf(w0, A[j],  fmaf(w1, A[j + 2],  w2 * A[j + 4]));
            float zB = fmaf(w0, Bv[j], fmaf(w1, Bv[j + 2], w2 * Bv[j + 4]));
            *(unsigned*)&Bz[(ll + j) * ST + c2] = cvtpk(zA, zB);
            *(unsigned*)&Bx[(ll + j) * ST + c2] = cvtpk(A[j + 4], Bv[j + 4]);
        }
    };

    LOAD(0);
    for (int ks = 0; ks < KSTEPS; ++ks) {
        #pragma unroll
        for (int j = 0; j < 4; ++j) { cp16(wsrc[j], wdst[j]); wsrc[j] += BK; }
        PACKB();
        __syncthreads();                           // drains cp16 (vmcnt) + B ds_writes (lgkm)
        if (ks < KSTEPS - 1) LOAD(ks + 1);
        short8 vz[4], vx[4];
        #pragma unroll
        for (int ni = 0; ni < 4; ++ni) {
            vz[ni] = *(const short8*)&Bz[bOff[ni]];
            vx[ni] = *(const short8*)&Bx[bOff[ni]];
        }
        #pragma unroll
        for (int mi = 0; mi < 4; ++mi) {
            short8 ap = *(const short8*)&As[aOffP[mi]];
            short8 ar = *(const short8*)&As[4096 + aOffP[mi]];
            #pragma unroll
            for (int ni = 0; ni < 4; ++ni) {
                accY[mi][ni] = __builtin_amdgcn_mfma_f32_16x16x32_bf16(ap, vz[ni], accY[mi][ni], 0, 0, 0);
                accR[mi][ni] = __builtin_amdgcn_mfma_f32_16x16x32_bf16(ar, vx[ni], accR[mi][ni], 0, 0, 0);
            }
        }
        __syncthreads();
    }

    #pragma unroll
    for (int mi = 0; mi < 4; ++mi)
        #pragma unroll
        for (int r = 0; r < 4; ++r) {
            const int o = o0 + wo + mi * 16 + fq * 4 + r;
            const float sc = sc_arr[o], sh = sh_arr[o], rb = res_b[o];
            const size_t orow = ((size_t)b * kCout + o) * kL + l0 + wl + fr;
            #pragma unroll
            for (int ni = 0; ni < 4; ++ni) {
                float yn = fmaxf(fmaf(accY[mi][ni][r], sc, sh), 0.f);
                float rr = accR[mi][ni][r] + rb;
                out[orow + ni * 16] = fmaxf(yn + rr, 0.f);
            }
        }
}

extern "C" void kernel_launch(void* const* d_in, const int* in_sizes, int n_in,
                              void* d_out, int out_size, void* d_ws, size_t ws_size,
                              hipStream_t stream)
{
    (void)in_sizes; (void)n_in; (void)out_size;
    const float* x     = (const float*)d_in[0];
    const float* sw    = (const float*)d_in[1];
    const float* pw_w  = (const float*)d_in[2];
    const float* gamma = (const float*)d_in[4];
    const float* beta  = (const float*)d_in[5];
    const float* res_w = (const float*)d_in[6];
    const float* res_b = (const float*)d_in[7];
    float* out = (float*)d_out;
    float* wsf = (float*)d_ws;

    if (ws_size >= W_BYTES) {
        unsigned short* Wbf = (unsigned short*)(wsf + W_WBF);
        k_init<<<161, 256, 0, stream>>>(pw_w, res_w, Wbf, wsf + W_SZ, wsf + W_G);
        k_prepc<<<256 * 32, 256, 0, stream>>>(x, sw, (unsigned short*)(wsf + W_ZC), wsf + W_SZ);
        k_gram2<<<256, 256, 0, stream>>>((const unsigned short*)(wsf + W_ZC), wsf + W_GPART);
        k_gred<<<256, 256, 0, stream>>>(wsf + W_GPART, wsf + W_G);
        k_bnp<<<kCout, 256, 0, stream>>>(wsf + W_G, wsf + W_SZ, Wbf, gamma, beta,
                                         wsf + W_SC, wsf + W_SH);
        k_out2<<<GRID_OUT, 256, 0, stream>>>(x, sw, Wbf, res_b,
                                             wsf + W_SC, wsf + W_SH, out);
    } else {
        unsigned short* Wbf = (unsigned short*)(wsf + F_WBF);
        k_init<<<161, 256, 0, stream>>>(pw_w, res_w, Wbf, wsf + F_SZ, wsf + F_G);
        k_gram_fb<<<512, 256, 0, stream>>>(x, sw, wsf + F_G, wsf + F_SZ);
        k_bnp<<<kCout, 256, 0, stream>>>(wsf + F_G, wsf + F_SZ, Wbf, gamma, beta,
                                         wsf + F_SC, wsf + F_SH);
        k_out2<<<GRID_OUT, 256, 0, stream>>>(x, sw, Wbf, res_b,
                                             wsf + F_SC, wsf + F_SH, out);
    }
}